// Round 1
// baseline (463.938 us; speedup 1.0000x reference)
//
#include <hip/hip_runtime.h>
#include <math.h>

// ---- static config (mirrors reference) ----
constexpr int BB  = 32;     // batch
constexpr int MM  = 20;     // max gt per image
constexpr int NCC = 80;     // classes
constexpr int RM  = 16;     // reg_max
constexpr int NOC = 144;    // channels per head
constexpr int AT  = 8400;   // anchors
constexpr int TK  = 10;     // topk
constexpr int BA  = BB * AT;  // 268800
constexpr int BM  = BB * MM;  // 640
constexpr float EPS_A   = 1e-9f;   // assigner EPS
constexpr float VCOEF   = 0.40528473456935108577551785283891f; // 4/pi^2

struct Lvl { const float* f; int o, w, hw; float s; };

__device__ inline Lvl level_of(int a, const float* f0, const float* f1, const float* f2){
  Lvl L;
  if (a < 6400)      { L.f = f0; L.o = a;        L.w = 80; L.hw = 6400; L.s = 8.f;  }
  else if (a < 8000) { L.f = f1; L.o = a - 6400; L.w = 40; L.hw = 1600; L.s = 16.f; }
  else               { L.f = f2; L.o = a - 8000; L.w = 20; L.hw = 400;  L.s = 32.f; }
  return L;
}

// CIoU exactly as reference (_ciou): b1 first operand, b2 second.
__device__ inline float ciou_f(float b1x1,float b1y1,float b1x2,float b1y2,
                               float b2x1,float b2y1,float b2x2,float b2y2){
  const float eps = 1e-7f;
  float w1 = b1x2 - b1x1, h1 = b1y2 - b1y1 + eps;
  float w2 = b2x2 - b2x1, h2 = b2y2 - b2y1 + eps;
  float iw = fminf(b1x2, b2x2) - fmaxf(b1x1, b2x1); iw = fmaxf(iw, 0.f);
  float ih = fminf(b1y2, b2y2) - fmaxf(b1y1, b2y1); ih = fmaxf(ih, 0.f);
  float inter = iw * ih;
  float uni = w1 * h1 + w2 * h2 - inter + eps;
  float iou = inter / uni;
  float cw = fmaxf(b1x2, b2x2) - fminf(b1x1, b2x1);
  float ch = fmaxf(b1y2, b2y2) - fminf(b1y1, b2y1);
  float c2 = cw * cw + ch * ch + eps;
  float dx = b2x1 + b2x2 - b1x1 - b1x2;
  float dy = b2y1 + b2y2 - b1y1 - b1y2;
  float rho2 = (dx * dx + dy * dy) * 0.25f;
  float dat = atanf(w2 / h2) - atanf(w1 / h1);
  float v = VCOEF * dat * dat;
  float alpha = v / (v - iou + (1.0f + eps));
  return iou - (rho2 / c2 + v * alpha);
}

__device__ inline unsigned long long shfl_xor_u64(unsigned long long v, int mask){
  int lo = __shfl_xor((int)(unsigned)(v & 0xFFFFFFFFull), mask);
  int hi = __shfl_xor((int)(unsigned)(v >> 32), mask);
  return ((unsigned long long)(unsigned)hi << 32) | (unsigned)lo;
}

__device__ inline void topk_insert(unsigned long long* top, unsigned long long key){
#pragma unroll
  for (int k = 0; k < TK; k++){
    unsigned long long cur = top[k];
    bool gt = key > cur;
    top[k] = gt ? key : cur;
    key    = gt ? cur : key;
  }
}

// ---------------- kernel 1: preprocess targets ----------------
// one block of 640 threads
__global__ void k_prep(const float* __restrict__ tgt, float* __restrict__ out5,
                       float* __restrict__ gtbox, int* __restrict__ gtlab,
                       float* __restrict__ gtmask, double* __restrict__ acc){
  int t = threadIdx.x; // 0..639
  for (int i = t; i < BM * 5; i += 640) out5[i] = 0.f;
  if (t < 8) acc[t] = 0.0;
  __syncthreads();
  // scatter row t -> (img, pos)
  {
    int img = (int)tgt[t * 6 + 0];
    int j = t;
    while (j > 0 && (int)tgt[(j - 1) * 6 + 0] == img) j--;
    int pos = t - j;
    if (img >= 0 && img < BB && pos < MM){
      for (int k = 0; k < 5; k++)
        out5[(img * MM + pos) * 5 + k] = tgt[t * 6 + 1 + k];
    }
  }
  __syncthreads();
  // per (b,m): label, xyxy, mask
  {
    float lab = out5[t * 5 + 0];
    float cx = out5[t * 5 + 1] * 640.f;
    float cy = out5[t * 5 + 2] * 640.f;
    float w  = out5[t * 5 + 3] * 640.f;
    float h  = out5[t * 5 + 4] * 640.f;
    float x1 = cx - w * 0.5f, y1 = cy - h * 0.5f;
    float x2 = cx + w * 0.5f, y2 = cy + h * 0.5f;
    gtbox[t * 4 + 0] = x1; gtbox[t * 4 + 1] = y1;
    gtbox[t * 4 + 2] = x2; gtbox[t * 4 + 3] = y2;
    gtlab[t] = (int)lab;
    gtmask[t] = ((x1 + y1 + x2 + y2) > 0.f) ? 1.f : 0.f;
  }
}

// ---------------- kernel 2: DFL decode + softplus sum ----------------
__global__ void k_decode(const float* __restrict__ f0, const float* __restrict__ f1,
                         const float* __restrict__ f2,
                         float* __restrict__ pbox, float* __restrict__ lse,
                         double* __restrict__ acc){
  int gid = blockIdx.x * blockDim.x + threadIdx.x;
  float sp = 0.f;
  if (gid < BA){
    int b = gid / AT, a = gid % AT;
    Lvl L = level_of(a, f0, f1, f2);
    const float* base = L.f + (size_t)b * NOC * L.hw + L.o;
    float ax = (float)(L.o % L.w) + 0.5f;
    float ay = (float)(L.o / L.w) + 0.5f;
    float d[4], ls[4];
#pragma unroll
    for (int s4 = 0; s4 < 4; s4++){
      float x[RM]; float mx = -1e30f;
#pragma unroll
      for (int j = 0; j < RM; j++){ x[j] = base[(size_t)(s4 * RM + j) * L.hw]; mx = fmaxf(mx, x[j]); }
      float sm = 0.f, dot = 0.f;
#pragma unroll
      for (int j = 0; j < RM; j++){ float e = expf(x[j] - mx); sm += e; dot += e * (float)j; }
      d[s4] = dot / sm;
      ls[s4] = mx + logf(sm);
    }
    size_t o4 = (size_t)gid * 4;
    pbox[o4 + 0] = ax - d[0]; pbox[o4 + 1] = ay - d[1];
    pbox[o4 + 2] = ax + d[2]; pbox[o4 + 3] = ay + d[3];
    lse[o4 + 0] = ls[0]; lse[o4 + 1] = ls[1]; lse[o4 + 2] = ls[2]; lse[o4 + 3] = ls[3];
    for (int c = 4 * RM; c < NOC; c++){
      float x = base[(size_t)c * L.hw];
      sp += fmaxf(x, 0.f) + log1pf(expf(-fabsf(x)));
    }
  }
  for (int off = 32; off; off >>= 1) sp += __shfl_down(sp, off);
  __shared__ float red[8];
  int wid = threadIdx.x >> 6, lid = threadIdx.x & 63;
  if (lid == 0) red[wid] = sp;
  __syncthreads();
  if (threadIdx.x == 0){
    float tot = 0.f; int nw = blockDim.x >> 6;
    for (int i = 0; i < nw; i++) tot += red[i];
    atomicAdd(&acc[4], (double)tot);
  }
}

// ---------------- kernel 3: overlaps/align rows + exact top-10 ----------------
// one wave (64 threads) per (b,m)
__global__ void k_align(const float* __restrict__ f0, const float* __restrict__ f1,
                        const float* __restrict__ f2,
                        const float* __restrict__ pbox,
                        const float* __restrict__ gtbox, const int* __restrict__ gtlab,
                        const float* __restrict__ gtmask,
                        float* __restrict__ ovl_arr, float* __restrict__ aln_arr,
                        int* __restrict__ topk){
  int pair = blockIdx.x; // 0..BM-1
  int b = pair / MM;
  int lane = threadIdx.x;
  float gx1 = gtbox[pair * 4 + 0], gy1 = gtbox[pair * 4 + 1];
  float gx2 = gtbox[pair * 4 + 2], gy2 = gtbox[pair * 4 + 3];
  int lab = gtlab[pair];
  float mg = gtmask[pair];
  unsigned long long top[TK];
#pragma unroll
  for (int k = 0; k < TK; k++) top[k] = 0ULL;
  size_t row = (size_t)pair * AT;
  for (int a = lane; a < AT; a += 64){
    float ovl = 0.f, aln = 0.f;
    if (mg > 0.f){
      Lvl L = level_of(a, f0, f1, f2);
      float ax = ((float)(L.o % L.w) + 0.5f) * L.s;
      float ay = ((float)(L.o / L.w) + 0.5f) * L.s;
      float mn = fminf(fminf(ax - gx1, ay - gy1), fminf(gx2 - ax, gy2 - ay));
      if (mn > EPS_A){
        size_t p4 = ((size_t)b * AT + a) * 4;
        float px1 = pbox[p4 + 0] * L.s, py1 = pbox[p4 + 1] * L.s;
        float px2 = pbox[p4 + 2] * L.s, py2 = pbox[p4 + 3] * L.s;
        float c = ciou_f(gx1, gy1, gx2, gy2, px1, py1, px2, py2);
        ovl = fmaxf(c, 0.f);
        float x = L.f[(size_t)b * NOC * L.hw + (size_t)(4 * RM + lab) * L.hw + L.o];
        float sc = 1.f / (1.f + expf(-x));
        aln = sqrtf(sc) * powf(ovl, 6.0f);
      }
    }
    ovl_arr[row + a] = ovl;
    aln_arr[row + a] = aln;
    unsigned long long key =
        ((unsigned long long)__float_as_uint(aln) << 32) |
        (unsigned long long)(0xFFFFFFFFu - (unsigned)a);
    topk_insert(top, key);
  }
  // butterfly merge across the wave
  for (int xm = 1; xm < 64; xm <<= 1){
    unsigned long long oth[TK];
#pragma unroll
    for (int k = 0; k < TK; k++) oth[k] = shfl_xor_u64(top[k], xm);
#pragma unroll
    for (int k = 0; k < TK; k++) topk_insert(top, oth[k]);
  }
  if (lane == 0){
    for (int k = 0; k < TK; k++){
      int a = (mg > 0.f) ? (int)(0xFFFFFFFFu - (unsigned)(top[k] & 0xFFFFFFFFull)) : -1;
      topk[pair * TK + k] = a;
    }
  }
}

// ---------------- kernel 4: per-anchor mask_pos bitmask + multi-gt resolve ----------------
__global__ void k_resolve(const float* __restrict__ gtbox, const float* __restrict__ gtmask,
                          const int* __restrict__ topk, const float* __restrict__ ovl_arr,
                          unsigned* __restrict__ mpos){
  int b = blockIdx.y;
  int a = blockIdx.x * 256 + threadIdx.x;
  __shared__ int   s_top[MM * TK];
  __shared__ float s_box[MM * 4];
  __shared__ float s_mg[MM];
  for (int i = threadIdx.x; i < MM * TK; i += 256) s_top[i] = topk[b * MM * TK + i];
  for (int i = threadIdx.x; i < MM * 4;  i += 256) s_box[i] = gtbox[b * MM * 4 + i];
  for (int i = threadIdx.x; i < MM;      i += 256) s_mg[i]  = gtmask[b * MM + i];
  __syncthreads();
  if (a >= AT) return;
  Lvl L = level_of(a, nullptr, nullptr, nullptr);
  float ax = ((float)(L.o % L.w) + 0.5f) * L.s;
  float ay = ((float)(L.o / L.w) + 0.5f) * L.s;
  unsigned bits = 0;
  for (int m = 0; m < MM; m++){
    if (s_mg[m] <= 0.f) continue;
    float mn = fminf(fminf(ax - s_box[m * 4 + 0], ay - s_box[m * 4 + 1]),
                     fminf(s_box[m * 4 + 2] - ax, s_box[m * 4 + 3] - ay));
    if (mn <= EPS_A) continue;
    bool intop = false;
#pragma unroll
    for (int k = 0; k < TK; k++) intop |= (s_top[m * TK + k] == a);
    if (intop) bits |= (1u << m);
  }
  if (__popc(bits) > 1){
    float best = -1.f; int bm = 0;
    for (int m = 0; m < MM; m++){
      float v = ovl_arr[((size_t)(b * MM + m)) * AT + a];
      if (v > best){ best = v; bm = m; }
    }
    bits = (1u << bm);
  }
  mpos[(size_t)b * AT + a] = bits;
}

// ---------------- kernel 5: per-(b,m) maxima over positives ----------------
__global__ void k_posmax(const float* __restrict__ aln_arr, const float* __restrict__ ovl_arr,
                         const unsigned* __restrict__ mpos,
                         float* __restrict__ pos_aln, float* __restrict__ pos_ovl){
  int pair = blockIdx.x;
  int b = pair / MM, m = pair % MM;
  int lane = threadIdx.x;
  float ma = 0.f, mo = 0.f;
  size_t row = (size_t)pair * AT;
  for (int a = lane; a < AT; a += 64){
    if ((mpos[(size_t)b * AT + a] >> m) & 1u){
      ma = fmaxf(ma, aln_arr[row + a]);
      mo = fmaxf(mo, ovl_arr[row + a]);
    }
  }
  for (int off = 32; off; off >>= 1){
    ma = fmaxf(ma, __shfl_down(ma, off));
    mo = fmaxf(mo, __shfl_down(mo, off));
  }
  if (lane == 0){ pos_aln[pair] = ma; pos_ovl[pair] = mo; }
}

// ---------------- kernel 6: per-anchor losses ----------------
__global__ void k_final(const float* __restrict__ f0, const float* __restrict__ f1,
                        const float* __restrict__ f2,
                        const float* __restrict__ pbox, const float* __restrict__ lse,
                        const float* __restrict__ aln_arr, const unsigned* __restrict__ mpos,
                        const float* __restrict__ gtbox, const int* __restrict__ gtlab,
                        const float* __restrict__ pos_aln, const float* __restrict__ pos_ovl,
                        double* __restrict__ acc){
  int b = blockIdx.y;
  int a = blockIdx.x * 256 + threadIdx.x;
  __shared__ float s_box[MM * 4];
  __shared__ int   s_lab[MM];
  __shared__ float s_pa[MM];
  __shared__ float s_po[MM];
  for (int i = threadIdx.x; i < MM * 4; i += 256) s_box[i] = gtbox[b * MM * 4 + i];
  for (int i = threadIdx.x; i < MM;     i += 256){
    s_lab[i] = gtlab[b * MM + i];
    s_pa[i]  = pos_aln[b * MM + i];
    s_po[i]  = pos_ovl[b * MM + i];
  }
  __syncthreads();
  float w_ = 0.f, boxp = 0.f, dflp = 0.f, clsp = 0.f;
  if (a < AT){
    unsigned bits = mpos[(size_t)b * AT + a];
    if (bits){
      int m = __ffs(bits) - 1;
      float alv = aln_arr[((size_t)(b * MM + m)) * AT + a];
      float norm = alv * s_po[m] / (s_pa[m] + EPS_A);
      w_ = norm;
      Lvl L = level_of(a, f0, f1, f2);
      const float* base = L.f + (size_t)b * NOC * L.hw + L.o;
      float ax = (float)(L.o % L.w) + 0.5f;
      float ay = (float)(L.o / L.w) + 0.5f;
      // target box in feature units
      float inv_s = 1.f / L.s;
      float tx1 = s_box[m * 4 + 0] * inv_s, ty1 = s_box[m * 4 + 1] * inv_s;
      float tx2 = s_box[m * 4 + 2] * inv_s, ty2 = s_box[m * 4 + 3] * inv_s;
      size_t p4 = ((size_t)b * AT + a) * 4;
      float px1 = pbox[p4 + 0], py1 = pbox[p4 + 1];
      float px2 = pbox[p4 + 2], py2 = pbox[p4 + 3];
      float iou = ciou_f(px1, py1, px2, py2, tx1, ty1, tx2, ty2);
      boxp = (1.f - iou) * w_;
      // DFL
      float tv[4];
      tv[0] = ax - tx1; tv[1] = ay - ty1; tv[2] = tx2 - ax; tv[3] = ty2 - ay;
      float dfl = 0.f;
#pragma unroll
      for (int s4 = 0; s4 < 4; s4++){
        float t = fminf(fmaxf(tv[s4], 0.f), (float)(RM - 1) - 0.01f);
        int tl = (int)t;
        float wl = (float)(tl + 1) - t;
        float L_ = lse[p4 + s4];
        float xl = base[(size_t)(s4 * RM + tl) * L.hw];
        float xr = base[(size_t)(s4 * RM + tl + 1) * L.hw];
        float nll_l = L_ - xl;
        float nll_r = L_ - xr;
        dfl += nll_l * wl + nll_r * (1.f - wl);
      }
      dflp = dfl * 0.25f * w_;
      // cls correction: x at target label * weight
      int lab = s_lab[m];
      float xc = base[(size_t)(4 * RM + lab) * L.hw];
      clsp = xc * w_;
    }
  }
  // block reduce 4 values
  __shared__ float red[4][4];
  float vals[4] = { w_, clsp, boxp, dflp };
  int wid = threadIdx.x >> 6, lid = threadIdx.x & 63;
#pragma unroll
  for (int i = 0; i < 4; i++){
    float v = vals[i];
    for (int off = 32; off; off >>= 1) v += __shfl_down(v, off);
    if (lid == 0) red[wid][i] = v;
    vals[i] = v;
  }
  __syncthreads();
  if (threadIdx.x == 0){
    float t0 = 0.f, t1 = 0.f, t2 = 0.f, t3 = 0.f;
    for (int w2 = 0; w2 < 4; w2++){
      t0 += red[w2][0]; t1 += red[w2][1]; t2 += red[w2][2]; t3 += red[w2][3];
    }
    atomicAdd(&acc[0], (double)t0);
    atomicAdd(&acc[1], (double)t1);
    atomicAdd(&acc[2], (double)t2);
    atomicAdd(&acc[3], (double)t3);
  }
}

// ---------------- kernel 7: finalize ----------------
__global__ void k_out(const double* __restrict__ acc, float* __restrict__ out){
  if (threadIdx.x == 0 && blockIdx.x == 0){
    double tss = acc[0] > 1.0 ? acc[0] : 1.0;
    double loss_box = acc[2] / tss;
    double loss_cls = (acc[4] - acc[1]) / tss;
    double loss_dfl = acc[3] / tss;
    float l0 = (float)(loss_box * 7.5);
    float l1 = (float)(loss_cls * 0.5);
    float l2 = (float)(loss_dfl * 1.5);
    out[0] = (l0 + l1 + l2) * 32.f;
    out[1] = l0;
    out[2] = l1;
    out[3] = l2;
  }
}

extern "C" void kernel_launch(void* const* d_in, const int* in_sizes, int n_in,
                              void* d_out, int out_size, void* d_ws, size_t ws_size,
                              hipStream_t stream) {
  const float* f0 = (const float*)d_in[0];
  const float* f1 = (const float*)d_in[1];
  const float* f2 = (const float*)d_in[2];
  const float* tg = (const float*)d_in[3];
  float* out = (float*)d_out;

  char* w = (char*)d_ws;
  size_t off = 0;
  auto alloc = [&](size_t bytes) -> void* {
    void* p = w + off;
    off += (bytes + 255) & ~(size_t)255;
    return p;
  };
  float*    pbox   = (float*)   alloc((size_t)BA * 4 * 4);
  float*    lse    = (float*)   alloc((size_t)BA * 4 * 4);
  float*    ovl    = (float*)   alloc((size_t)BM * AT * 4);
  float*    aln    = (float*)   alloc((size_t)BM * AT * 4);
  int*      topk   = (int*)     alloc((size_t)BM * TK * 4);
  float*    gtbox  = (float*)   alloc((size_t)BM * 4 * 4);
  int*      gtlab  = (int*)     alloc((size_t)BM * 4);
  float*    gtmask = (float*)   alloc((size_t)BM * 4);
  float*    out5   = (float*)   alloc((size_t)BM * 5 * 4);
  unsigned* mpos   = (unsigned*)alloc((size_t)BA * 4);
  float*    pa     = (float*)   alloc((size_t)BM * 4);
  float*    po     = (float*)   alloc((size_t)BM * 4);
  double*   acc    = (double*)  alloc(8 * 8);

  k_prep<<<1, 640, 0, stream>>>(tg, out5, gtbox, gtlab, gtmask, acc);
  k_decode<<<(BA + 255) / 256, 256, 0, stream>>>(f0, f1, f2, pbox, lse, acc);
  k_align<<<BM, 64, 0, stream>>>(f0, f1, f2, pbox, gtbox, gtlab, gtmask, ovl, aln, topk);
  k_resolve<<<dim3((AT + 255) / 256, BB), 256, 0, stream>>>(gtbox, gtmask, topk, ovl, mpos);
  k_posmax<<<BM, 64, 0, stream>>>(aln, ovl, mpos, pa, po);
  k_final<<<dim3((AT + 255) / 256, BB), 256, 0, stream>>>(f0, f1, f2, pbox, lse, aln, mpos,
                                                          gtbox, gtlab, pa, po, acc);
  k_out<<<1, 64, 0, stream>>>(acc, out);
}

// Round 2
// 332.846 us; speedup vs baseline: 1.3939x; 1.3939x over previous
//
#include <hip/hip_runtime.h>
#include <math.h>

// ---- static config (mirrors reference) ----
constexpr int BB  = 32;     // batch
constexpr int MM  = 20;     // max gt per image
constexpr int NCC = 80;     // classes
constexpr int RM  = 16;     // reg_max
constexpr int NOC = 144;    // channels per head
constexpr int AT  = 8400;   // anchors
constexpr int TK  = 10;     // topk
constexpr int BA  = BB * AT;  // 268800
constexpr int BM  = BB * MM;  // 640
constexpr float EPS_A   = 1e-9f;
constexpr float VCOEF   = 0.40528473456935108577551785283891f; // 4/pi^2

struct Lvl { const float* f; int o, w, hw; float s; };

__device__ inline Lvl level_of(int a, const float* f0, const float* f1, const float* f2){
  Lvl L;
  if (a < 6400)      { L.f = f0; L.o = a;        L.w = 80; L.hw = 6400; L.s = 8.f;  }
  else if (a < 8000) { L.f = f1; L.o = a - 6400; L.w = 40; L.hw = 1600; L.s = 16.f; }
  else               { L.f = f2; L.o = a - 8000; L.w = 20; L.hw = 400;  L.s = 32.f; }
  return L;
}

__device__ inline float frcp(float x){ return __builtin_amdgcn_rcpf(x); }

// fast atan, |err| < ~2e-6 over full range (tolerance is 2% relative)
__device__ inline float fast_atan(float x){
  float ax = fabsf(x);
  bool big = ax > 1.f;
  float z = big ? frcp(ax) : ax;
  float z2 = z * z;
  float p = fmaf(z2, -0.0117212f, 0.0526533f);
  p = fmaf(z2, p, -0.1164329f);
  p = fmaf(z2, p, 0.1935435f);
  p = fmaf(z2, p, -0.3326235f);
  p = fmaf(z2, p, 0.9999773f);
  float r = z * p;
  r = big ? 1.57079632679f - r : r;
  return copysignf(r, x);
}

// CIoU (reference _ciou) with fast divisions + single atan via difference identity
__device__ inline float ciou_f(float b1x1,float b1y1,float b1x2,float b1y2,
                               float b2x1,float b2y1,float b2x2,float b2y2){
  const float eps = 1e-7f;
  float w1 = b1x2 - b1x1, h1 = b1y2 - b1y1 + eps;
  float w2 = b2x2 - b2x1, h2 = b2y2 - b2y1 + eps;
  float iw = fmaxf(fminf(b1x2, b2x2) - fmaxf(b1x1, b2x1), 0.f);
  float ih = fmaxf(fminf(b1y2, b2y2) - fmaxf(b1y1, b2y1), 0.f);
  float inter = iw * ih;
  float uni = w1 * h1 + w2 * h2 - inter + eps;
  float iou = inter * frcp(uni);
  float cw = fmaxf(b1x2, b2x2) - fminf(b1x1, b2x1);
  float ch = fmaxf(b1y2, b2y2) - fminf(b1y1, b2y1);
  float c2 = cw * cw + ch * ch + eps;
  float dx = b2x1 + b2x2 - b1x1 - b1x2;
  float dy = b2y1 + b2y2 - b1y1 - b1y2;
  float rho2 = (dx * dx + dy * dy) * 0.25f;
  // atan(r2)-atan(r1) = atan((r2-r1)/(1+r1*r2)) for r1,r2 >= 0
  float r1 = w1 * frcp(h1), r2 = w2 * frcp(h2);
  float dat = fast_atan((r2 - r1) * frcp(fmaf(r1, r2, 1.f)));
  float v = VCOEF * dat * dat;
  float alpha = v * frcp(v - iou + (1.0f + eps));
  return iou - (rho2 * frcp(c2) + v * alpha);
}

__device__ inline unsigned long long shfl_xor_u64(unsigned long long v, int mask){
  int lo = __shfl_xor((int)(unsigned)(v & 0xFFFFFFFFull), mask);
  int hi = __shfl_xor((int)(unsigned)(v >> 32), mask);
  return ((unsigned long long)(unsigned)hi << 32) | (unsigned)lo;
}

__device__ inline void topk_insert(unsigned long long* top, unsigned long long key){
#pragma unroll
  for (int k = 0; k < TK; k++){
    unsigned long long cur = top[k];
    bool gt = key > cur;
    top[k] = gt ? key : cur;
    key    = gt ? cur : key;
  }
}

// ---------------- kernel 1: preprocess targets ----------------
__global__ void k_prep(const float* __restrict__ tgt, float* __restrict__ out5,
                       float* __restrict__ gtbox, int* __restrict__ gtlab,
                       float* __restrict__ gtmask, int* __restrict__ pa_i,
                       int* __restrict__ po_i, double* __restrict__ acc){
  int t = threadIdx.x; // 0..639
  for (int i = t; i < BM * 5; i += 640) out5[i] = 0.f;
  if (t < 8) acc[t] = 0.0;
  pa_i[t] = 0; po_i[t] = 0;
  __syncthreads();
  {
    int img = (int)tgt[t * 6 + 0];
    int j = t;
    while (j > 0 && (int)tgt[(j - 1) * 6 + 0] == img) j--;
    int pos = t - j;
    if (img >= 0 && img < BB && pos < MM){
      for (int k = 0; k < 5; k++)
        out5[(img * MM + pos) * 5 + k] = tgt[t * 6 + 1 + k];
    }
  }
  __syncthreads();
  {
    float lab = out5[t * 5 + 0];
    float cx = out5[t * 5 + 1] * 640.f;
    float cy = out5[t * 5 + 2] * 640.f;
    float w  = out5[t * 5 + 3] * 640.f;
    float h  = out5[t * 5 + 4] * 640.f;
    float x1 = cx - w * 0.5f, y1 = cy - h * 0.5f;
    float x2 = cx + w * 0.5f, y2 = cy + h * 0.5f;
    gtbox[t * 4 + 0] = x1; gtbox[t * 4 + 1] = y1;
    gtbox[t * 4 + 2] = x2; gtbox[t * 4 + 3] = y2;
    gtlab[t] = (int)lab;
    gtmask[t] = ((x1 + y1 + x2 + y2) > 0.f) ? 1.f : 0.f;
  }
}

// ---------------- kernel 2: DFL decode + softplus sum ----------------
__global__ void k_decode(const float* __restrict__ f0, const float* __restrict__ f1,
                         const float* __restrict__ f2,
                         float4* __restrict__ pbox, float4* __restrict__ lse,
                         double* __restrict__ acc){
  int gid = blockIdx.x * blockDim.x + threadIdx.x;
  float sp = 0.f;
  if (gid < BA){
    int b = gid / AT, a = gid % AT;
    Lvl L = level_of(a, f0, f1, f2);
    const float* base = L.f + (size_t)b * NOC * L.hw + L.o;
    float ax = (float)(L.o % L.w) + 0.5f;
    float ay = (float)(L.o / L.w) + 0.5f;
    float d[4], ls[4];
#pragma unroll
    for (int s4 = 0; s4 < 4; s4++){
      float x[RM]; float mx = -1e30f;
#pragma unroll
      for (int j = 0; j < RM; j++){ x[j] = base[(size_t)(s4 * RM + j) * L.hw]; mx = fmaxf(mx, x[j]); }
      float sm = 0.f, dot = 0.f;
#pragma unroll
      for (int j = 0; j < RM; j++){ float e = __expf(x[j] - mx); sm += e; dot += e * (float)j; }
      d[s4] = dot * frcp(sm);
      ls[s4] = mx + __logf(sm);
    }
    pbox[gid] = make_float4(ax - d[0], ay - d[1], ax + d[2], ay + d[3]);
    lse[gid]  = make_float4(ls[0], ls[1], ls[2], ls[3]);
    const float* cb = base + (size_t)(4 * RM) * L.hw;
    for (int c = 0; c < NCC; c++){
      float x = cb[(size_t)c * L.hw];
      sp += fmaxf(x, 0.f) + __logf(1.f + __expf(-fabsf(x)));
    }
  }
  for (int off = 32; off; off >>= 1) sp += __shfl_down(sp, off);
  __shared__ float red[4];
  int wid = threadIdx.x >> 6, lid = threadIdx.x & 63;
  if (lid == 0) red[wid] = sp;
  __syncthreads();
  if (threadIdx.x == 0){
    float tot = red[0] + red[1] + red[2] + red[3];
    atomicAdd(&acc[4], (double)tot);
  }
}

// ---------------- kernel 3: overlaps/align rows + exact top-10 ----------------
// one block (256 threads = 4 waves) per (b,m)
__global__ __launch_bounds__(256) void k_align(
    const float* __restrict__ f0, const float* __restrict__ f1,
    const float* __restrict__ f2, const float4* __restrict__ pbox,
    const float* __restrict__ gtbox, const int* __restrict__ gtlab,
    const float* __restrict__ gtmask,
    float* __restrict__ ovl_arr, float* __restrict__ aln_arr,
    int* __restrict__ topk){
  int pair = blockIdx.x;
  int b = pair / MM;
  int tid = threadIdx.x;
  float gx1 = gtbox[pair * 4 + 0], gy1 = gtbox[pair * 4 + 1];
  float gx2 = gtbox[pair * 4 + 2], gy2 = gtbox[pair * 4 + 3];
  int lab = gtlab[pair];
  float mg = gtmask[pair];
  unsigned long long top[TK];
#pragma unroll
  for (int k = 0; k < TK; k++) top[k] = 0ULL;
  size_t row = (size_t)pair * AT;
  for (int a = tid; a < AT; a += 256){
    float ovl = 0.f, aln = 0.f;
    if (mg > 0.f){
      Lvl L = level_of(a, f0, f1, f2);
      float ax = ((float)(L.o % L.w) + 0.5f) * L.s;
      float ay = ((float)(L.o / L.w) + 0.5f) * L.s;
      float mn = fminf(fminf(ax - gx1, ay - gy1), fminf(gx2 - ax, gy2 - ay));
      if (mn > EPS_A){
        float4 pb = pbox[b * AT + a];
        float c = ciou_f(gx1, gy1, gx2, gy2,
                         pb.x * L.s, pb.y * L.s, pb.z * L.s, pb.w * L.s);
        ovl = fmaxf(c, 0.f);
        float x = L.f[(size_t)b * NOC * L.hw + (size_t)(4 * RM + lab) * L.hw + L.o];
        float sc = frcp(1.f + __expf(-x));
        float o2 = ovl * ovl;
        aln = sqrtf(sc) * (o2 * o2 * o2);
      }
    }
    ovl_arr[row + a] = ovl;
    aln_arr[row + a] = aln;
    unsigned long long key =
        ((unsigned long long)__float_as_uint(aln) << 32) |
        (unsigned long long)(0xFFFFFFFFu - (unsigned)a);
    topk_insert(top, key);
  }
  // butterfly merge within wave
  for (int xm = 1; xm < 64; xm <<= 1){
    unsigned long long oth[TK];
#pragma unroll
    for (int k = 0; k < TK; k++) oth[k] = shfl_xor_u64(top[k], xm);
#pragma unroll
    for (int k = 0; k < TK; k++) topk_insert(top, oth[k]);
  }
  // cross-wave merge via LDS
  __shared__ unsigned long long s_keys[4 * TK];
  int wid = tid >> 6, lid = tid & 63;
  if (lid == 0){
#pragma unroll
    for (int k = 0; k < TK; k++) s_keys[wid * TK + k] = top[k];
  }
  __syncthreads();
  if (tid == 0){
    unsigned long long fin[TK];
#pragma unroll
    for (int k = 0; k < TK; k++) fin[k] = s_keys[k];
    for (int i = TK; i < 4 * TK; i++) topk_insert(fin, s_keys[i]);
    for (int k = 0; k < TK; k++){
      int a = (mg > 0.f) ? (int)(0xFFFFFFFFu - (unsigned)(fin[k] & 0xFFFFFFFFull)) : -1;
      topk[pair * TK + k] = a;
    }
  }
}

// ---------------- kernel 4: mask_pos bitmask + multi-gt resolve + pos maxima ----------------
__global__ void k_resolve(const float* __restrict__ gtbox, const float* __restrict__ gtmask,
                          const int* __restrict__ topk, const float* __restrict__ ovl_arr,
                          const float* __restrict__ aln_arr,
                          unsigned* __restrict__ mpos,
                          int* __restrict__ pa_i, int* __restrict__ po_i){
  int b = blockIdx.y;
  int a = blockIdx.x * 256 + threadIdx.x;
  __shared__ int   s_top[MM * TK];
  __shared__ float s_box[MM * 4];
  __shared__ float s_mg[MM];
  for (int i = threadIdx.x; i < MM * TK; i += 256) s_top[i] = topk[b * MM * TK + i];
  for (int i = threadIdx.x; i < MM * 4;  i += 256) s_box[i] = gtbox[b * MM * 4 + i];
  for (int i = threadIdx.x; i < MM;      i += 256) s_mg[i]  = gtmask[b * MM + i];
  __syncthreads();
  if (a >= AT) return;
  Lvl L = level_of(a, nullptr, nullptr, nullptr);
  float ax = ((float)(L.o % L.w) + 0.5f) * L.s;
  float ay = ((float)(L.o / L.w) + 0.5f) * L.s;
  unsigned bits = 0;
  for (int m = 0; m < MM; m++){
    if (s_mg[m] <= 0.f) continue;
    float mn = fminf(fminf(ax - s_box[m * 4 + 0], ay - s_box[m * 4 + 1]),
                     fminf(s_box[m * 4 + 2] - ax, s_box[m * 4 + 3] - ay));
    if (mn <= EPS_A) continue;
    bool intop = false;
#pragma unroll
    for (int k = 0; k < TK; k++) intop |= (s_top[m * TK + k] == a);
    if (intop) bits |= (1u << m);
  }
  if (__popc(bits) > 1){
    float best = -1.f; int bm = 0;
    for (int m = 0; m < MM; m++){
      float v = ovl_arr[((size_t)(b * MM + m)) * AT + a];
      if (v > best){ best = v; bm = m; }
    }
    bits = (1u << bm);
  }
  mpos[(size_t)b * AT + a] = bits;
  if (bits){
    int m = __ffs(bits) - 1;
    size_t idx = ((size_t)(b * MM + m)) * AT + a;
    atomicMax(&pa_i[b * MM + m], __float_as_int(aln_arr[idx]));
    atomicMax(&po_i[b * MM + m], __float_as_int(ovl_arr[idx]));
  }
}

// ---------------- kernel 5: per-anchor losses ----------------
__global__ void k_final(const float* __restrict__ f0, const float* __restrict__ f1,
                        const float* __restrict__ f2,
                        const float4* __restrict__ pbox, const float4* __restrict__ lse,
                        const float* __restrict__ aln_arr, const unsigned* __restrict__ mpos,
                        const float* __restrict__ gtbox, const int* __restrict__ gtlab,
                        const int* __restrict__ pa_i, const int* __restrict__ po_i,
                        double* __restrict__ acc){
  int b = blockIdx.y;
  int a = blockIdx.x * 256 + threadIdx.x;
  __shared__ float s_box[MM * 4];
  __shared__ int   s_lab[MM];
  __shared__ float s_pa[MM];
  __shared__ float s_po[MM];
  for (int i = threadIdx.x; i < MM * 4; i += 256) s_box[i] = gtbox[b * MM * 4 + i];
  for (int i = threadIdx.x; i < MM;     i += 256){
    s_lab[i] = gtlab[b * MM + i];
    s_pa[i]  = __int_as_float(pa_i[b * MM + i]);
    s_po[i]  = __int_as_float(po_i[b * MM + i]);
  }
  __syncthreads();
  float w_ = 0.f, boxp = 0.f, dflp = 0.f, clsp = 0.f;
  if (a < AT){
    unsigned bits = mpos[(size_t)b * AT + a];
    if (bits){
      int m = __ffs(bits) - 1;
      float alv = aln_arr[((size_t)(b * MM + m)) * AT + a];
      w_ = alv * s_po[m] * frcp(s_pa[m] + EPS_A);
      Lvl L = level_of(a, f0, f1, f2);
      const float* base = L.f + (size_t)b * NOC * L.hw + L.o;
      float ax = (float)(L.o % L.w) + 0.5f;
      float ay = (float)(L.o / L.w) + 0.5f;
      float inv_s = frcp(L.s);
      float tx1 = s_box[m * 4 + 0] * inv_s, ty1 = s_box[m * 4 + 1] * inv_s;
      float tx2 = s_box[m * 4 + 2] * inv_s, ty2 = s_box[m * 4 + 3] * inv_s;
      float4 pb = pbox[b * AT + a];
      float iou = ciou_f(pb.x, pb.y, pb.z, pb.w, tx1, ty1, tx2, ty2);
      boxp = (1.f - iou) * w_;
      float4 L4 = lse[b * AT + a];
      float lsv[4] = { L4.x, L4.y, L4.z, L4.w };
      float tv[4];
      tv[0] = ax - tx1; tv[1] = ay - ty1; tv[2] = tx2 - ax; tv[3] = ty2 - ay;
      float dfl = 0.f;
#pragma unroll
      for (int s4 = 0; s4 < 4; s4++){
        float t = fminf(fmaxf(tv[s4], 0.f), (float)(RM - 1) - 0.01f);
        int tl = (int)t;
        float wl = (float)(tl + 1) - t;
        float xl = base[(size_t)(s4 * RM + tl) * L.hw];
        float xr = base[(size_t)(s4 * RM + tl + 1) * L.hw];
        dfl += (lsv[s4] - xl) * wl + (lsv[s4] - xr) * (1.f - wl);
      }
      dflp = dfl * 0.25f * w_;
      int lab = s_lab[m];
      clsp = base[(size_t)(4 * RM + lab) * L.hw] * w_;
    }
  }
  __shared__ float red[4][4];
  float vals[4] = { w_, clsp, boxp, dflp };
  int wid = threadIdx.x >> 6, lid = threadIdx.x & 63;
#pragma unroll
  for (int i = 0; i < 4; i++){
    float v = vals[i];
    for (int off = 32; off; off >>= 1) v += __shfl_down(v, off);
    if (lid == 0) red[wid][i] = v;
  }
  __syncthreads();
  if (threadIdx.x == 0){
    float t0 = 0.f, t1 = 0.f, t2 = 0.f, t3 = 0.f;
    for (int w2 = 0; w2 < 4; w2++){
      t0 += red[w2][0]; t1 += red[w2][1]; t2 += red[w2][2]; t3 += red[w2][3];
    }
    atomicAdd(&acc[0], (double)t0);
    atomicAdd(&acc[1], (double)t1);
    atomicAdd(&acc[2], (double)t2);
    atomicAdd(&acc[3], (double)t3);
  }
}

// ---------------- kernel 6: finalize ----------------
__global__ void k_out(const double* __restrict__ acc, float* __restrict__ out){
  if (threadIdx.x == 0 && blockIdx.x == 0){
    double tss = acc[0] > 1.0 ? acc[0] : 1.0;
    double loss_box = acc[2] / tss;
    double loss_cls = (acc[4] - acc[1]) / tss;
    double loss_dfl = acc[3] / tss;
    float l0 = (float)(loss_box * 7.5);
    float l1 = (float)(loss_cls * 0.5);
    float l2 = (float)(loss_dfl * 1.5);
    out[0] = (l0 + l1 + l2) * 32.f;
    out[1] = l0;
    out[2] = l1;
    out[3] = l2;
  }
}

extern "C" void kernel_launch(void* const* d_in, const int* in_sizes, int n_in,
                              void* d_out, int out_size, void* d_ws, size_t ws_size,
                              hipStream_t stream) {
  const float* f0 = (const float*)d_in[0];
  const float* f1 = (const float*)d_in[1];
  const float* f2 = (const float*)d_in[2];
  const float* tg = (const float*)d_in[3];
  float* out = (float*)d_out;

  char* w = (char*)d_ws;
  size_t off = 0;
  auto alloc = [&](size_t bytes) -> void* {
    void* p = w + off;
    off += (bytes + 255) & ~(size_t)255;
    return p;
  };
  float4*   pbox   = (float4*)  alloc((size_t)BA * 4 * 4);
  float4*   lse    = (float4*)  alloc((size_t)BA * 4 * 4);
  float*    ovl    = (float*)   alloc((size_t)BM * AT * 4);
  float*    aln    = (float*)   alloc((size_t)BM * AT * 4);
  int*      topk   = (int*)     alloc((size_t)BM * TK * 4);
  float*    gtbox  = (float*)   alloc((size_t)BM * 4 * 4);
  int*      gtlab  = (int*)     alloc((size_t)BM * 4);
  float*    gtmask = (float*)   alloc((size_t)BM * 4);
  float*    out5   = (float*)   alloc((size_t)BM * 5 * 4);
  unsigned* mpos   = (unsigned*)alloc((size_t)BA * 4);
  int*      pa     = (int*)     alloc((size_t)BM * 4);
  int*      po     = (int*)     alloc((size_t)BM * 4);
  double*   acc    = (double*)  alloc(8 * 8);

  k_prep<<<1, 640, 0, stream>>>(tg, out5, gtbox, gtlab, gtmask, pa, po, acc);
  k_decode<<<(BA + 255) / 256, 256, 0, stream>>>(f0, f1, f2, pbox, lse, acc);
  k_align<<<BM, 256, 0, stream>>>(f0, f1, f2, pbox, gtbox, gtlab, gtmask, ovl, aln, topk);
  k_resolve<<<dim3((AT + 255) / 256, BB), 256, 0, stream>>>(gtbox, gtmask, topk, ovl, aln,
                                                            mpos, pa, po);
  k_final<<<dim3((AT + 255) / 256, BB), 256, 0, stream>>>(f0, f1, f2, pbox, lse, aln, mpos,
                                                          gtbox, gtlab, pa, po, acc);
  k_out<<<1, 64, 0, stream>>>(acc, out);
}

// Round 3
// 323.776 us; speedup vs baseline: 1.4329x; 1.0280x over previous
//
#include <hip/hip_runtime.h>
#include <math.h>

// ---- static config (mirrors reference) ----
constexpr int BB  = 32;     // batch
constexpr int MM  = 20;     // max gt per image
constexpr int NCC = 80;     // classes
constexpr int RM  = 16;     // reg_max
constexpr int NOC = 144;    // channels per head
constexpr int AT  = 8400;   // anchors
constexpr int TK  = 10;     // topk
constexpr int BA  = BB * AT;  // 268800
constexpr int BM  = BB * MM;  // 640
constexpr int MAXPOS = BM * TK; // 6400 max positive anchors
constexpr float EPS_A = 1e-9f;
constexpr float VCOEF = 0.40528473456935108577551785283891f; // 4/pi^2

struct Lvl { const float* f; int o, w, hw; float s; };

__device__ inline Lvl level_of(int a, const float* f0, const float* f1, const float* f2){
  Lvl L;
  if (a < 6400)      { L.f = f0; L.o = a;        L.w = 80; L.hw = 6400; L.s = 8.f;  }
  else if (a < 8000) { L.f = f1; L.o = a - 6400; L.w = 40; L.hw = 1600; L.s = 16.f; }
  else               { L.f = f2; L.o = a - 8000; L.w = 20; L.hw = 400;  L.s = 32.f; }
  return L;
}

__device__ inline float frcp(float x){ return __builtin_amdgcn_rcpf(x); }

// fast atan, |err| < ~2e-6
__device__ inline float fast_atan(float x){
  float ax = fabsf(x);
  bool big = ax > 1.f;
  float z = big ? frcp(ax) : ax;
  float z2 = z * z;
  float p = fmaf(z2, -0.0117212f, 0.0526533f);
  p = fmaf(z2, p, -0.1164329f);
  p = fmaf(z2, p, 0.1935435f);
  p = fmaf(z2, p, -0.3326235f);
  p = fmaf(z2, p, 0.9999773f);
  float r = z * p;
  r = big ? 1.57079632679f - r : r;
  return copysignf(r, x);
}

__device__ inline float ciou_f(float b1x1,float b1y1,float b1x2,float b1y2,
                               float b2x1,float b2y1,float b2x2,float b2y2){
  const float eps = 1e-7f;
  float w1 = b1x2 - b1x1, h1 = b1y2 - b1y1 + eps;
  float w2 = b2x2 - b2x1, h2 = b2y2 - b2y1 + eps;
  float iw = fmaxf(fminf(b1x2, b2x2) - fmaxf(b1x1, b2x1), 0.f);
  float ih = fmaxf(fminf(b1y2, b2y2) - fmaxf(b1y1, b2y1), 0.f);
  float inter = iw * ih;
  float uni = w1 * h1 + w2 * h2 - inter + eps;
  float iou = inter * frcp(uni);
  float cw = fmaxf(b1x2, b2x2) - fminf(b1x1, b2x1);
  float ch = fmaxf(b1y2, b2y2) - fminf(b1y1, b2y1);
  float c2 = cw * cw + ch * ch + eps;
  float dx = b2x1 + b2x2 - b1x1 - b1x2;
  float dy = b2y1 + b2y2 - b1y1 - b1y2;
  float rho2 = (dx * dx + dy * dy) * 0.25f;
  float r1 = w1 * frcp(h1), r2 = w2 * frcp(h2);
  float dat = fast_atan((r2 - r1) * frcp(fmaf(r1, r2, 1.f)));
  float v = VCOEF * dat * dat;
  float alpha = v * frcp(v - iou + (1.0f + eps));
  return iou - (rho2 * frcp(c2) + v * alpha);
}

__device__ inline unsigned long long shfl_xor_u64(unsigned long long v, int mask){
  int lo = __shfl_xor((int)(unsigned)(v & 0xFFFFFFFFull), mask);
  int hi = __shfl_xor((int)(unsigned)(v >> 32), mask);
  return ((unsigned long long)(unsigned)hi << 32) | (unsigned)lo;
}

__device__ inline void topk_insert(unsigned long long* top, unsigned long long key){
#pragma unroll
  for (int k = 0; k < TK; k++){
    unsigned long long cur = top[k];
    bool gt = key > cur;
    top[k] = gt ? key : cur;
    key    = gt ? cur : key;
  }
}

// ---------------- kernel 1: preprocess targets ----------------
__global__ void k_prep(const float* __restrict__ tgt, float* __restrict__ out5,
                       float* __restrict__ gtbox, int* __restrict__ gtlab,
                       float* __restrict__ gtmask, int* __restrict__ pa_i,
                       int* __restrict__ po_i, double* __restrict__ acc){
  int t = threadIdx.x; // 0..639
  for (int i = t; i < BM * 5; i += 640) out5[i] = 0.f;
  if (t < 8) acc[t] = 0.0;
  pa_i[t] = 0; po_i[t] = 0;
  __syncthreads();
  {
    int img = (int)tgt[t * 6 + 0];
    int j = t;
    while (j > 0 && (int)tgt[(j - 1) * 6 + 0] == img) j--;
    int pos = t - j;
    if (img >= 0 && img < BB && pos < MM){
      for (int k = 0; k < 5; k++)
        out5[(img * MM + pos) * 5 + k] = tgt[t * 6 + 1 + k];
    }
  }
  __syncthreads();
  {
    float lab = out5[t * 5 + 0];
    float cx = out5[t * 5 + 1] * 640.f;
    float cy = out5[t * 5 + 2] * 640.f;
    float w  = out5[t * 5 + 3] * 640.f;
    float h  = out5[t * 5 + 4] * 640.f;
    float x1 = cx - w * 0.5f, y1 = cy - h * 0.5f;
    float x2 = cx + w * 0.5f, y2 = cy + h * 0.5f;
    gtbox[t * 4 + 0] = x1; gtbox[t * 4 + 1] = y1;
    gtbox[t * 4 + 2] = x2; gtbox[t * 4 + 3] = y2;
    gtlab[t] = (int)lab;
    gtmask[t] = ((x1 + y1 + x2 + y2) > 0.f) ? 1.f : 0.f;
  }
}

// ---------------- kernel 2: DFL decode + softplus sum ----------------
// __launch_bounds__(256,4): VGPR cap 128 = 4 waves/SIMD, exactly what the
// 4200-wave grid supplies; lets all 64 dfl loads stay in flight.
__global__ __launch_bounds__(256, 4) void k_decode(
    const float* __restrict__ f0, const float* __restrict__ f1,
    const float* __restrict__ f2,
    float4* __restrict__ pbox, float4* __restrict__ lse,
    double* __restrict__ acc){
  int gid = blockIdx.x * blockDim.x + threadIdx.x;
  float sp = 0.f;
  {
    int b = gid / AT, a = gid % AT;
    Lvl L = level_of(a, f0, f1, f2);
    const float* base = L.f + (size_t)b * NOC * L.hw + L.o;
    float ax = (float)(L.o % L.w) + 0.5f;
    float ay = (float)(L.o / L.w) + 0.5f;
    // load all 64 dfl logits up-front (max MLP)
    float x[4][RM];
#pragma unroll
    for (int s4 = 0; s4 < 4; s4++)
#pragma unroll
      for (int j = 0; j < RM; j++)
        x[s4][j] = base[(size_t)(s4 * RM + j) * L.hw];
    float d[4], ls[4];
#pragma unroll
    for (int s4 = 0; s4 < 4; s4++){
      float mx = -1e30f;
#pragma unroll
      for (int j = 0; j < RM; j++) mx = fmaxf(mx, x[s4][j]);
      float sm = 0.f, dot = 0.f;
#pragma unroll
      for (int j = 0; j < RM; j++){ float e = __expf(x[s4][j] - mx); sm += e; dot += e * (float)j; }
      d[s4] = dot * frcp(sm);
      ls[s4] = mx + __logf(sm);
    }
    pbox[gid] = make_float4(ax - d[0], ay - d[1], ax + d[2], ay + d[3]);
    lse[gid]  = make_float4(ls[0], ls[1], ls[2], ls[3]);
    const float* cb = base + (size_t)(4 * RM) * L.hw;
#pragma unroll
    for (int c = 0; c < NCC; c++){
      float xv = cb[(size_t)c * L.hw];
      sp += fmaxf(xv, 0.f) + __logf(1.f + __expf(-fabsf(xv)));
    }
  }
  for (int off = 32; off; off >>= 1) sp += __shfl_down(sp, off);
  __shared__ float red[4];
  int wid = threadIdx.x >> 6, lid = threadIdx.x & 63;
  if (lid == 0) red[wid] = sp;
  __syncthreads();
  if (threadIdx.x == 0){
    float tot = red[0] + red[1] + red[2] + red[3];
    atomicAdd(&acc[4], (double)tot);
  }
}

// ---------------- kernel 3: candidate-rect top-10 + scatter ----------------
// one block per (b,m); iterates only anchors inside the gt rect (~<=1000)
__global__ __launch_bounds__(256) void k_align(
    const float* __restrict__ f0, const float* __restrict__ f1,
    const float* __restrict__ f2, const float4* __restrict__ pbox,
    const float* __restrict__ gtbox, const int* __restrict__ gtlab,
    const float* __restrict__ gtmask,
    unsigned* __restrict__ mpos, unsigned* __restrict__ list,
    int* __restrict__ count){
  int pair = blockIdx.x;
  int b = pair / MM, m = pair % MM;
  if (gtmask[pair] <= 0.f) return;  // block-uniform exit
  int tid = threadIdx.x;
  float gx1 = gtbox[pair * 4 + 0], gy1 = gtbox[pair * 4 + 1];
  float gx2 = gtbox[pair * 4 + 2], gy2 = gtbox[pair * 4 + 3];
  int lab = gtlab[pair];
  const float* fs[3] = { f0, f1, f2 };
  const int   wdt[3] = { 80, 40, 20 };
  const int   hwv[3] = { 6400, 1600, 400 };
  const int   aoff[3]= { 0, 6400, 8000 };
  const float sv[3]  = { 8.f, 16.f, 32.f };
  int rx0[3], nx[3], ry0[3], pre[3]; int total = 0;
#pragma unroll
  for (int l = 0; l < 3; l++){
    float inv = frcp(sv[l]);
    int x0 = max(0, (int)floorf(gx1 * inv - 0.5f));
    int x1 = min(wdt[l] - 1, (int)ceilf(gx2 * inv - 0.5f));
    int y0 = max(0, (int)floorf(gy1 * inv - 0.5f));
    int y1 = min(wdt[l] - 1, (int)ceilf(gy2 * inv - 0.5f));
    int nxx = max(0, x1 - x0 + 1), nyy = max(0, y1 - y0 + 1);
    rx0[l] = x0; ry0[l] = y0; nx[l] = nxx; pre[l] = total; total += nxx * nyy;
  }
  unsigned long long top[TK];
#pragma unroll
  for (int k = 0; k < TK; k++) top[k] = 0ULL;
  for (int t = tid; t < total; t += 256){
    int l = (t >= pre[2]) ? 2 : ((t >= pre[1]) ? 1 : 0);
    int r = t - pre[l];
    int iy = ry0[l] + r / nx[l];
    int ix = rx0[l] + r % nx[l];
    float s = sv[l];
    float ax = ((float)ix + 0.5f) * s;
    float ay = ((float)iy + 0.5f) * s;
    float mn = fminf(fminf(ax - gx1, ay - gy1), fminf(gx2 - ax, gy2 - ay));
    if (mn > EPS_A){
      int o = iy * wdt[l] + ix;
      int a = aoff[l] + o;
      float4 pb = pbox[b * AT + a];
      float c = ciou_f(gx1, gy1, gx2, gy2, pb.x * s, pb.y * s, pb.z * s, pb.w * s);
      float ovl = fmaxf(c, 0.f);
      float xv = fs[l][(size_t)b * NOC * hwv[l] + (size_t)(4 * RM + lab) * hwv[l] + o];
      float sc = frcp(1.f + __expf(-xv));
      float o2 = ovl * ovl;
      float aln = sqrtf(sc) * (o2 * o2 * o2);
      unsigned long long key =
          ((unsigned long long)__float_as_uint(aln) << 32) |
          (unsigned long long)(0xFFFFFFFFu - (unsigned)a);
      topk_insert(top, key);
    }
  }
  for (int xm = 1; xm < 64; xm <<= 1){
    unsigned long long oth[TK];
#pragma unroll
    for (int k = 0; k < TK; k++) oth[k] = shfl_xor_u64(top[k], xm);
#pragma unroll
    for (int k = 0; k < TK; k++) topk_insert(top, oth[k]);
  }
  __shared__ unsigned long long s_keys[4 * TK];
  int wid = tid >> 6, lid = tid & 63;
  if (lid == 0){
#pragma unroll
    for (int k = 0; k < TK; k++) s_keys[wid * TK + k] = top[k];
  }
  __syncthreads();
  if (tid == 0){
    unsigned long long fin[TK];
#pragma unroll
    for (int k = 0; k < TK; k++) fin[k] = s_keys[k];
    for (int i = TK; i < 4 * TK; i++) topk_insert(fin, s_keys[i]);
    for (int k = 0; k < TK; k++){
      unsigned a = 0xFFFFFFFFu - (unsigned)(fin[k] & 0xFFFFFFFFull);
      if (a < (unsigned)AT){
        unsigned old = atomicOr(&mpos[(size_t)b * AT + a], 1u << m);
        if (old == 0){
          int i = atomicAdd(count, 1);
          list[i] = ((unsigned)b << 14) | a;
        }
      }
    }
  }
}

// ---------------- kernel 4: resolve multi-claims, pos maxima (compact list) ----------------
__global__ __launch_bounds__(256) void k_resolve(
    const float* __restrict__ f0, const float* __restrict__ f1,
    const float* __restrict__ f2, const float4* __restrict__ pbox,
    const float* __restrict__ gtbox, const int* __restrict__ gtlab,
    const float* __restrict__ gtmask, const unsigned* __restrict__ mpos,
    const unsigned* __restrict__ list, const int* __restrict__ count,
    unsigned* __restrict__ list_m, float* __restrict__ list_aln,
    int* __restrict__ pa_i, int* __restrict__ po_i){
  int i = blockIdx.x * 256 + threadIdx.x;
  if (i >= *count) return;
  unsigned pk = list[i];
  int b = pk >> 14, a = pk & 0x3FFF;
  unsigned bits = mpos[(size_t)b * AT + a];
  Lvl L = level_of(a, f0, f1, f2);
  float ax = ((float)(L.o % L.w) + 0.5f) * L.s;
  float ay = ((float)(L.o / L.w) + 0.5f) * L.s;
  float4 pb = pbox[b * AT + a];
  float px1 = pb.x * L.s, py1 = pb.y * L.s, px2 = pb.z * L.s, py2 = pb.w * L.s;
  int m; float ovl;
  if (__popc(bits) > 1){
    // argmax over ALL gts of masked overlap (first-max tie-break)
    float best = -1.f; int bm = 0;
    for (int mm = 0; mm < MM; mm++){
      float v = 0.f;
      if (gtmask[b * MM + mm] > 0.f){
        float x1 = gtbox[(b * MM + mm) * 4 + 0], y1 = gtbox[(b * MM + mm) * 4 + 1];
        float x2 = gtbox[(b * MM + mm) * 4 + 2], y2 = gtbox[(b * MM + mm) * 4 + 3];
        float mn = fminf(fminf(ax - x1, ay - y1), fminf(x2 - ax, y2 - ay));
        if (mn > EPS_A)
          v = fmaxf(ciou_f(x1, y1, x2, y2, px1, py1, px2, py2), 0.f);
      }
      if (v > best){ best = v; bm = mm; }
    }
    m = bm; ovl = fmaxf(best, 0.f);
  } else {
    m = __ffs(bits) - 1;
    float x1 = gtbox[(b * MM + m) * 4 + 0], y1 = gtbox[(b * MM + m) * 4 + 1];
    float x2 = gtbox[(b * MM + m) * 4 + 2], y2 = gtbox[(b * MM + m) * 4 + 3];
    ovl = fmaxf(ciou_f(x1, y1, x2, y2, px1, py1, px2, py2), 0.f);
  }
  int lab = gtlab[b * MM + m];
  float xv = L.f[(size_t)b * NOC * L.hw + (size_t)(4 * RM + lab) * L.hw + L.o];
  float sc = frcp(1.f + __expf(-xv));
  float o2 = ovl * ovl;
  float aln = sqrtf(sc) * (o2 * o2 * o2);
  list_m[i] = (unsigned)m;
  list_aln[i] = aln;
  atomicMax(&pa_i[b * MM + m], __float_as_int(aln));
  atomicMax(&po_i[b * MM + m], __float_as_int(ovl));
}

// ---------------- kernel 5: per-positive losses (compact list) ----------------
__global__ __launch_bounds__(256) void k_final(
    const float* __restrict__ f0, const float* __restrict__ f1,
    const float* __restrict__ f2,
    const float4* __restrict__ pbox, const float4* __restrict__ lse,
    const float* __restrict__ gtbox, const int* __restrict__ gtlab,
    const int* __restrict__ pa_i, const int* __restrict__ po_i,
    const unsigned* __restrict__ list, const unsigned* __restrict__ list_m,
    const float* __restrict__ list_aln, const int* __restrict__ count,
    double* __restrict__ acc){
  int i = blockIdx.x * 256 + threadIdx.x;
  float w_ = 0.f, clsp = 0.f, boxp = 0.f, dflp = 0.f;
  if (i < *count){
    unsigned pk = list[i];
    int b = pk >> 14, a = pk & 0x3FFF;
    int m = (int)list_m[i];
    float aln = list_aln[i];
    float pa = __int_as_float(pa_i[b * MM + m]);
    float po = __int_as_float(po_i[b * MM + m]);
    w_ = aln * po * frcp(pa + EPS_A);
    Lvl L = level_of(a, f0, f1, f2);
    const float* base = L.f + (size_t)b * NOC * L.hw + L.o;
    float ax = (float)(L.o % L.w) + 0.5f;
    float ay = (float)(L.o / L.w) + 0.5f;
    float inv_s = frcp(L.s);
    float tx1 = gtbox[(b * MM + m) * 4 + 0] * inv_s, ty1 = gtbox[(b * MM + m) * 4 + 1] * inv_s;
    float tx2 = gtbox[(b * MM + m) * 4 + 2] * inv_s, ty2 = gtbox[(b * MM + m) * 4 + 3] * inv_s;
    float4 pb = pbox[b * AT + a];
    float iou = ciou_f(pb.x, pb.y, pb.z, pb.w, tx1, ty1, tx2, ty2);
    boxp = (1.f - iou) * w_;
    float4 L4 = lse[b * AT + a];
    float lsv[4] = { L4.x, L4.y, L4.z, L4.w };
    float tv[4] = { ax - tx1, ay - ty1, tx2 - ax, ty2 - ay };
    float dfl = 0.f;
#pragma unroll
    for (int s4 = 0; s4 < 4; s4++){
      float t = fminf(fmaxf(tv[s4], 0.f), (float)(RM - 1) - 0.01f);
      int tl = (int)t;
      float wl = (float)(tl + 1) - t;
      float xl = base[(size_t)(s4 * RM + tl) * L.hw];
      float xr = base[(size_t)(s4 * RM + tl + 1) * L.hw];
      dfl += (lsv[s4] - xl) * wl + (lsv[s4] - xr) * (1.f - wl);
    }
    dflp = dfl * 0.25f * w_;
    int lab = gtlab[b * MM + m];
    clsp = base[(size_t)(4 * RM + lab) * L.hw] * w_;
  }
  __shared__ float red[4][4];
  float vals[4] = { w_, clsp, boxp, dflp };
  int wid = threadIdx.x >> 6, lid = threadIdx.x & 63;
#pragma unroll
  for (int j = 0; j < 4; j++){
    float v = vals[j];
    for (int off = 32; off; off >>= 1) v += __shfl_down(v, off);
    if (lid == 0) red[wid][j] = v;
  }
  __syncthreads();
  if (threadIdx.x == 0){
    float t0 = 0.f, t1 = 0.f, t2 = 0.f, t3 = 0.f;
    for (int w2 = 0; w2 < 4; w2++){
      t0 += red[w2][0]; t1 += red[w2][1]; t2 += red[w2][2]; t3 += red[w2][3];
    }
    atomicAdd(&acc[0], (double)t0);
    atomicAdd(&acc[1], (double)t1);
    atomicAdd(&acc[2], (double)t2);
    atomicAdd(&acc[3], (double)t3);
  }
}

// ---------------- kernel 6: finalize ----------------
__global__ void k_out(const double* __restrict__ acc, float* __restrict__ out){
  if (threadIdx.x == 0 && blockIdx.x == 0){
    double tss = acc[0] > 1.0 ? acc[0] : 1.0;
    double loss_box = acc[2] / tss;
    double loss_cls = (acc[4] - acc[1]) / tss;
    double loss_dfl = acc[3] / tss;
    float l0 = (float)(loss_box * 7.5);
    float l1 = (float)(loss_cls * 0.5);
    float l2 = (float)(loss_dfl * 1.5);
    out[0] = (l0 + l1 + l2) * 32.f;
    out[1] = l0;
    out[2] = l1;
    out[3] = l2;
  }
}

extern "C" void kernel_launch(void* const* d_in, const int* in_sizes, int n_in,
                              void* d_out, int out_size, void* d_ws, size_t ws_size,
                              hipStream_t stream) {
  const float* f0 = (const float*)d_in[0];
  const float* f1 = (const float*)d_in[1];
  const float* f2 = (const float*)d_in[2];
  const float* tg = (const float*)d_in[3];
  float* out = (float*)d_out;

  char* w = (char*)d_ws;
  size_t off = 0;
  auto alloc = [&](size_t bytes) -> void* {
    void* p = w + off;
    off += (bytes + 255) & ~(size_t)255;
    return p;
  };
  float4*   pbox    = (float4*)  alloc((size_t)BA * 16);
  float4*   lse     = (float4*)  alloc((size_t)BA * 16);
  float*    gtbox   = (float*)   alloc((size_t)BM * 16);
  int*      gtlab   = (int*)     alloc((size_t)BM * 4);
  float*    gtmask  = (float*)   alloc((size_t)BM * 4);
  float*    out5    = (float*)   alloc((size_t)BM * 20);
  unsigned* mpos    = (unsigned*)alloc((size_t)BA * 4);   // zeroed below (with count)
  int*      count   = (int*)     alloc(4);
  unsigned* list    = (unsigned*)alloc((size_t)MAXPOS * 4);
  unsigned* list_m  = (unsigned*)alloc((size_t)MAXPOS * 4);
  float*    list_aln= (float*)   alloc((size_t)MAXPOS * 4);
  int*      pa      = (int*)     alloc((size_t)BM * 4);
  int*      po      = (int*)     alloc((size_t)BM * 4);
  double*   acc     = (double*)  alloc(8 * 8);

  // zero mpos + count (contiguous in the arena: BA*4 is 256-aligned, count follows)
  hipMemsetAsync(mpos, 0, (size_t)BA * 4 + 256, stream);

  k_prep<<<1, 640, 0, stream>>>(tg, out5, gtbox, gtlab, gtmask, pa, po, acc);
  k_decode<<<BA / 256, 256, 0, stream>>>(f0, f1, f2, pbox, lse, acc);
  k_align<<<BM, 256, 0, stream>>>(f0, f1, f2, pbox, gtbox, gtlab, gtmask,
                                  mpos, list, count);
  k_resolve<<<MAXPOS / 256, 256, 0, stream>>>(f0, f1, f2, pbox, gtbox, gtlab, gtmask,
                                              mpos, list, count, list_m, list_aln, pa, po);
  k_final<<<MAXPOS / 256, 256, 0, stream>>>(f0, f1, f2, pbox, lse, gtbox, gtlab,
                                            pa, po, list, list_m, list_aln, count, acc);
  k_out<<<1, 64, 0, stream>>>(acc, out);
}